// Round 3
// baseline (762.720 us; speedup 1.0000x reference)
//
#include <hip/hip_runtime.h>

using short8  = __attribute__((ext_vector_type(8))) short;
using floatx4 = __attribute__((ext_vector_type(4))) float;

// T and AGG live in channel-quarter-blocked layout: [quarter 0..3][node 0..N)[32 ch] bf16.
// Each quarter = N*64B = 3.2MB < 4MiB per-XCD L2, and the aggregate kernel pins
// quarter q to XCD pair {2q,2q+1} via blockIdx%8, so row gathers become L2 hits.

// ---------- bf16 helpers ----------
static __device__ __forceinline__ float bf2f(unsigned short u) {
    union { unsigned u; float f; } v; v.u = ((unsigned)u) << 16; return v.f;
}
static __device__ __forceinline__ unsigned short f2bf(float f) {
    union { float f; unsigned u; } v; v.f = f;
    unsigned r = v.u + 0x7FFFu + ((v.u >> 16) & 1u);   // round-to-nearest-even
    return (unsigned short)(r >> 16);
}

// ---------- fused: degree histogram + all weight transposes (independent work) ----------
__global__ void histw_kernel(const int* __restrict__ dst, int* __restrict__ cnt, int E,
                             const float* __restrict__ Win, const float* __restrict__ Wg,
                             const float* __restrict__ Wout,
                             unsigned short* __restrict__ WinT, unsigned short* __restrict__ WgT,
                             unsigned short* __restrict__ WoutT) {
    int HB = (E + 255) >> 8;
    int b = blockIdx.x;
    if (b < HB) {
        int i = b * 256 + threadIdx.x;
        if (i < E) atomicAdd(&cnt[dst[i]], 1);
    } else {
        int i = (b - HB) * 256 + threadIdx.x;
        if (i < 16384) {                       // Win 128x128
            int m = i & 127, k = i >> 7;
            WinT[m * 128 + k] = f2bf(Win[i]);
        } else if (i < 81920) {                // Wg 4x128x128
            int j = i - 16384;
            int m = j & 127, k = (j >> 7) & 127, mat = j >> 14;
            WgT[mat * 16384 + m * 128 + k] = f2bf(Wg[j]);
        } else if (i < 90112) {                // Wout 128x64
            int j = i - 81920;
            int m = j % 64, k = j / 64;
            WoutT[m * 128 + k] = f2bf(Wout[j]);
        }
    }
}

// ---------- single-kernel exclusive scan over cnt[0..n), nb <= 256 blocks ----------
__global__ __launch_bounds__(256) void scanall_kernel(const int* __restrict__ cnt,
        unsigned* __restrict__ bsum, unsigned* __restrict__ boff, unsigned* __restrict__ done,
        int* __restrict__ rowptr, int* __restrict__ cursor,
        float* __restrict__ dis, float* __restrict__ selfn, int n, int nb) {
    __shared__ int s[256];
    __shared__ int s2[256];
    __shared__ int flag_agg;
    __shared__ int blkoff;
    const int b = blockIdx.x, tid = threadIdx.x;
    int i = b * 256 + tid;
    int cc = (i < n) ? cnt[i] : 0;
    s[tid] = cc;
    __syncthreads();
    for (int off = 1; off < 256; off <<= 1) {   // inclusive scan in LDS
        int t = s[tid];
        int a = (tid >= off) ? s[tid - off] : 0;
        __syncthreads();
        s[tid] = t + a;
        __syncthreads();
    }
    if (tid == 0) {
        atomicExch(&bsum[b], (unsigned)s[255] | 0x80000000u);   // publish block total
        __threadfence();                                        // release
        unsigned t = atomicAdd(done, 1u);
        flag_agg = (t == (unsigned)(nb - 1)) ? 1 : 0;           // last arrival aggregates
    }
    __syncthreads();
    if (flag_agg) {
        __threadfence();                                        // acquire
        unsigned val = (tid < nb) ? (atomicOr(&bsum[tid], 0u) & 0x7fffffffu) : 0u;
        s2[tid] = (int)val;
        __syncthreads();
        for (int off = 1; off < 256; off <<= 1) {
            int t = s2[tid];
            int a = (tid >= off) ? s2[tid - off] : 0;
            __syncthreads();
            s2[tid] = t + a;
            __syncthreads();
        }
        if (tid < nb)
            atomicExch(&boff[tid], ((unsigned)s2[tid] - val) | 0x80000000u); // exclusive
    }
    if (tid == 0) {
        unsigned vv;
        while (((vv = atomicOr(&boff[b], 0u)) & 0x80000000u) == 0u)
            __builtin_amdgcn_s_sleep(8);
        blkoff = (int)(vv & 0x7fffffffu);
    }
    __syncthreads();
    if (i < n) {
        int pre = blkoff + s[tid] - cc;       // exclusive prefix
        rowptr[i] = pre;
        cursor[i] = pre;
        float d = (float)cc + 1.0f;           // deg = in-degree + self-loop
        dis[i] = rsqrtf(d);
        selfn[i] = 1.0f / d;
        if (i == n - 1) rowptr[n] = pre + cc;
    }
}

// ---------- CSR fill: packed {src, w=dis[s]*dis[d]} per edge (8B scattered store) ----------
__global__ void fill_kernel(const int* __restrict__ src, const int* __restrict__ dst,
        int* __restrict__ cursor, const float* __restrict__ dis,
        unsigned long long* __restrict__ epack, int E) {
    int i = blockIdx.x * 256 + threadIdx.x;
    if (i < E) {
        int s = src[i], d = dst[i];
        int p = atomicAdd(&cursor[d], 1);
        float w = dis[s] * dis[d];            // edge weight, constant across all 4 layers
        unsigned long long rec = (unsigned long long)(unsigned)s |
                                 ((unsigned long long)__float_as_uint(w) << 32);
        epack[p] = rec;
    }
}

// ---------- fused startup: h0 = x@W1 + b1 (bf16 row-major), t0 = h0@W2 (bf16 blocked) ----------
__global__ __launch_bounds__(256) void mgemm2_kernel(
        const float* __restrict__ X,
        const unsigned short* __restrict__ W1T, const float* __restrict__ b1,
        const unsigned short* __restrict__ W2T,
        unsigned short* __restrict__ H0, unsigned short* __restrict__ T0, int nrows) {
    __shared__ unsigned short Al[64 * 136];
    __shared__ unsigned short Wl[128 * 136];
    const int tid   = threadIdx.x;
    const int w     = tid >> 6;
    const int lane  = tid & 63;
    const int col_l = lane & 15;
    const int quad  = lane >> 4;
    const int row_base = blockIdx.x * 64;

#pragma unroll
    for (int it = 0; it < 8; ++it) {
        int idx = it * 256 + tid;
        int r = idx >> 5, c4 = idx & 31;
        int gr = row_base + r; if (gr >= nrows) gr = nrows - 1;
        float4 v = *(const float4*)&X[(size_t)gr * 128 + c4 * 4];
        ushort4 u;
        u.x = f2bf(v.x); u.y = f2bf(v.y); u.z = f2bf(v.z); u.w = f2bf(v.w);
        *(ushort4*)&Al[r * 136 + c4 * 4] = u;
    }
#pragma unroll
    for (int it = 0; it < 8; ++it) {
        int idx = it * 256 + tid;
        int r = idx >> 4, ch = idx & 15;
        *(float4*)&Wl[r * 136 + ch * 8] = *(const float4*)&W1T[(size_t)r * 128 + ch * 8];
    }
    __syncthreads();

    short8 af[4];
    const int arow = w * 16 + col_l;
#pragma unroll
    for (int ks = 0; ks < 4; ++ks)
        af[ks] = *(const short8*)&Al[arow * 136 + ks * 32 + quad * 8];

    floatx4 acc[8];
#pragma unroll
    for (int ct = 0; ct < 8; ++ct) {
        acc[ct] = (floatx4){0.f, 0.f, 0.f, 0.f};
#pragma unroll
        for (int ks = 0; ks < 4; ++ks) {
            short8 bf = *(const short8*)&Wl[(ct * 16 + col_l) * 136 + ks * 32 + quad * 8];
            acc[ct] = __builtin_amdgcn_mfma_f32_16x16x32_bf16(af[ks], bf, acc[ct], 0, 0, 0);
        }
    }
    __syncthreads();   // all LDS reads done before overwrite

#pragma unroll
    for (int ct = 0; ct < 8; ++ct) {
        int col = ct * 16 + col_l;
        float bv = b1[col];
#pragma unroll
        for (int r = 0; r < 4; ++r) {
            int row_l = w * 16 + quad * 4 + r;
            float o = acc[ct][r] + bv;
            unsigned short ob = f2bf(o);
            Al[row_l * 136 + col] = ob;
            int gr = row_base + row_l;
            if (gr < nrows) H0[(size_t)gr * 128 + col] = ob;
        }
    }
#pragma unroll
    for (int it = 0; it < 8; ++it) {
        int idx = it * 256 + tid;
        int r = idx >> 4, ch = idx & 15;
        *(float4*)&Wl[r * 136 + ch * 8] = *(const float4*)&W2T[(size_t)r * 128 + ch * 8];
    }
    __syncthreads();

#pragma unroll
    for (int ks = 0; ks < 4; ++ks)
        af[ks] = *(const short8*)&Al[arow * 136 + ks * 32 + quad * 8];
#pragma unroll
    for (int ct = 0; ct < 8; ++ct) {
        acc[ct] = (floatx4){0.f, 0.f, 0.f, 0.f};
#pragma unroll
        for (int ks = 0; ks < 4; ++ks) {
            short8 bf = *(const short8*)&Wl[(ct * 16 + col_l) * 136 + ks * 32 + quad * 8];
            acc[ct] = __builtin_amdgcn_mfma_f32_16x16x32_bf16(af[ks], bf, acc[ct], 0, 0, 0);
        }
    }
#pragma unroll
    for (int ct = 0; ct < 8; ++ct) {
        int col = ct * 16 + col_l;
        int q = col >> 5, c32 = col & 31;
#pragma unroll
        for (int r = 0; r < 4; ++r) {
            int gr = row_base + w * 16 + quad * 4 + r;
            if (gr < nrows)
                T0[((size_t)q * nrows + gr) * 32 + c32] = f2bf(acc[ct][r]);
        }
    }
}

// ---------- fused BN(+skip+relu+ACC[bf16]) -> MFMA GEMM ----------
// AGGB read in blocked layout; bf16 T output (OB16) written in blocked layout.
template<int MO, bool STAGE_ACC, bool OB16>
__global__ __launch_bounds__(256) void mgemm_bn_kernel(
        const unsigned short* __restrict__ AGGB, const float* __restrict__ stats,
        const float* __restrict__ gamma, const float* __restrict__ beta,
        const unsigned short* __restrict__ XSKIP, unsigned short* __restrict__ ACC,
        const unsigned short* __restrict__ WT, const float* __restrict__ bias,
        void* __restrict__ C, int nrows, float inv_n, int do_skip, int first) {
    constexpr int NT = MO / 16;
    __shared__ unsigned short Al[64 * 136];
    __shared__ unsigned short Wl[MO * 136];
    __shared__ float ABl[256];
    const int tid   = threadIdx.x;
    const int w     = tid >> 6;
    const int lane  = tid & 63;
    const int col_l = lane & 15;
    const int quad  = lane >> 4;
    const int row_base = blockIdx.x * 64;

    if (tid < 128) {
        float m = stats[tid] * inv_n;
        float var = stats[128 + tid] * inv_n - m * m;
        float inv = rsqrtf(var + 1e-5f);
        float Ax = inv * gamma[tid];
        ABl[tid] = Ax;
        ABl[128 + tid] = beta[tid] - m * Ax;
    }
#pragma unroll
    for (int it = 0; it < MO / 16; ++it) {
        int idx = it * 256 + tid;
        int r = idx >> 4, ch = idx & 15;
        *(float4*)&Wl[r * 136 + ch * 8] = *(const float4*)&WT[(size_t)r * 128 + ch * 8];
    }
    __syncthreads();

#pragma unroll
    for (int it = 0; it < 8; ++it) {
        int idx = it * 256 + tid;
        int r = idx >> 5, c4 = idx & 31;
        int gr = row_base + r;
        ushort4 hu = make_ushort4(0, 0, 0, 0);
        if (gr < nrows) {
            // blocked AGG: quarter = c4>>3, channel-in-quarter = (c4&7)*4
            ushort4 xb = *(const ushort4*)&AGGB[((size_t)(c4 >> 3) * nrows + gr) * 32 + (c4 & 7) * 4];
            float4 Av = ((const float4*)ABl)[c4];
            float4 Bv = ((const float4*)ABl)[32 + c4];
            float4 t;
            t.x = fmaf(bf2f(xb.x), Av.x, Bv.x);
            t.y = fmaf(bf2f(xb.y), Av.y, Bv.y);
            t.z = fmaf(bf2f(xb.z), Av.z, Bv.z);
            t.w = fmaf(bf2f(xb.w), Av.w, Bv.w);
            if (do_skip) {
                ushort4 sk = *(const ushort4*)&XSKIP[(size_t)gr * 128 + c4 * 4];
                t.x = fmaf(0.5f, bf2f(sk.x), t.x);
                t.y = fmaf(0.5f, bf2f(sk.y), t.y);
                t.z = fmaf(0.5f, bf2f(sk.z), t.z);
                t.w = fmaf(0.5f, bf2f(sk.w), t.w);
            }
            t.x = fmaxf(t.x, 0.f); t.y = fmaxf(t.y, 0.f);
            t.z = fmaxf(t.z, 0.f); t.w = fmaxf(t.w, 0.f);
            float4 a;
            if (first) {
                a = t;
            } else {
                ushort4 ab = *(const ushort4*)&ACC[(size_t)gr * 128 + c4 * 4];
                a.x = bf2f(ab.x) + t.x;
                a.y = bf2f(ab.y) + t.y;
                a.z = bf2f(ab.z) + t.z;
                a.w = bf2f(ab.w) + t.w;
            }
            float4 sv;
            if (STAGE_ACC) sv = a; else sv = t;
            hu.x = f2bf(sv.x); hu.y = f2bf(sv.y); hu.z = f2bf(sv.z); hu.w = f2bf(sv.w);
            if (!STAGE_ACC) {
                ushort4 au;
                au.x = f2bf(a.x); au.y = f2bf(a.y); au.z = f2bf(a.z); au.w = f2bf(a.w);
                *(ushort4*)&ACC[(size_t)gr * 128 + c4 * 4] = au;
            }
        }
        *(ushort4*)&Al[r * 136 + c4 * 4] = hu;
    }
    __syncthreads();

    short8 af[4];
    const int arow = w * 16 + col_l;
#pragma unroll
    for (int ks = 0; ks < 4; ++ks)
        af[ks] = *(const short8*)&Al[arow * 136 + ks * 32 + quad * 8];

    floatx4 acc[NT];
#pragma unroll
    for (int ct = 0; ct < NT; ++ct) {
        acc[ct] = (floatx4){0.f, 0.f, 0.f, 0.f};
#pragma unroll
        for (int ks = 0; ks < 4; ++ks) {
            short8 bf = *(const short8*)&Wl[(ct * 16 + col_l) * 136 + ks * 32 + quad * 8];
            acc[ct] = __builtin_amdgcn_mfma_f32_16x16x32_bf16(af[ks], bf, acc[ct], 0, 0, 0);
        }
    }

#pragma unroll
    for (int ct = 0; ct < NT; ++ct) {
        int col = ct * 16 + col_l;
        float bv = bias ? bias[col] : 0.f;
#pragma unroll
        for (int r = 0; r < 4; ++r) {
            int gr = row_base + w * 16 + quad * 4 + r;
            if (gr < nrows) {
                float o = acc[ct][r] + bv;
                if (OB16)
                    ((unsigned short*)C)[((size_t)(col >> 5) * nrows + gr) * 32 + (col & 31)] = f2bf(o);
                else
                    ((float*)C)[(size_t)gr * MO + col] = o;
            }
        }
    }
}

// ---------- CSR gather aggregation over channel-quarter-blocked T ----------
// blockIdx%8 pins quarter q=(blockIdx%8)>>1 to one XCD pair; each wave handles one
// node at a time: 4 lane-groups of 16 process 4 edges concurrently (64B row-quarter
// per edge), unroll-2 per group for MLP; shfl_xor(16/32) reduces groups.
__global__ __launch_bounds__(256) void aggregate_kernel(
        const unsigned short* __restrict__ T,      // [4][n][32] bf16
        const int* __restrict__ rowptr, const unsigned long long* __restrict__ epack,
        const float* __restrict__ selfn,
        unsigned short* __restrict__ AGGB,         // [4][n][32] bf16
        int n, int qw) {                            // qw = waves per quarter
    const int tid  = threadIdx.x;
    const int w    = tid >> 6;
    const int lane = tid & 63;
    const int g    = lane >> 4;          // edge group 0..3
    const int cl   = (lane & 15) * 2;    // channel-in-quarter (even)
    const int xid  = blockIdx.x & 7;
    const int q    = xid >> 1;
    const int s    = xid & 1;
    const int k    = blockIdx.x >> 3;
    const int wq   = (k * 2 + s) * 4 + w;          // wave index within quarter
    const unsigned short* Tq = T + (size_t)q * n * 32;
    unsigned short* Aq = AGGB + (size_t)q * n * 32;

    for (int v = wq; v < n; v += qw) {
        int e0 = rowptr[v], e1 = rowptr[v + 1];
        float ax = 0.f, ay = 0.f;
        if (g == 0) {                               // self-loop seeds group 0
            ushort2 tv = *(const ushort2*)&Tq[(size_t)v * 32 + cl];
            float sn = selfn[v];
            ax = bf2f(tv.x) * sn; ay = bf2f(tv.y) * sn;
        }
        int e = e0 + g;
        for (; e + 4 < e1; e += 8) {
            unsigned long long d0 = __builtin_nontemporal_load(&epack[e]);
            unsigned long long d1 = __builtin_nontemporal_load(&epack[e + 4]);
            unsigned u0 = (unsigned)d0, u1 = (unsigned)d1;
            ushort2 t0 = *(const ushort2*)&Tq[(size_t)u0 * 32 + cl];
            ushort2 t1 = *(const ushort2*)&Tq[(size_t)u1 * 32 + cl];
            float w0 = __uint_as_float((unsigned)(d0 >> 32));
            float w1 = __uint_as_float((unsigned)(d1 >> 32));
            ax = fmaf(w0, bf2f(t0.x), ax); ay = fmaf(w0, bf2f(t0.y), ay);
            ax = fmaf(w1, bf2f(t1.x), ax); ay = fmaf(w1, bf2f(t1.y), ay);
        }
        if (e < e1) {
            unsigned long long d0 = __builtin_nontemporal_load(&epack[e]);
            unsigned u0 = (unsigned)d0;
            ushort2 t0 = *(const ushort2*)&Tq[(size_t)u0 * 32 + cl];
            float w0 = __uint_as_float((unsigned)(d0 >> 32));
            ax = fmaf(w0, bf2f(t0.x), ax); ay = fmaf(w0, bf2f(t0.y), ay);
        }
        ax += __shfl_xor(ax, 16);
        ay += __shfl_xor(ay, 16);
        ax += __shfl_xor(ax, 32);
        ay += __shfl_xor(ay, 32);
        if (g == 0) {
            ushort2 o; o.x = f2bf(ax); o.y = f2bf(ay);
            *(ushort2*)&Aq[(size_t)v * 32 + cl] = o;
        }
    }
}

// ---------- BN stats (sum, sumsq per channel) over blocked bf16 AGG ----------
__global__ __launch_bounds__(256) void bn_stats_kernel(const unsigned short* __restrict__ AGGB,
        float* __restrict__ stats, int n) {
    __shared__ float s1[128], s2[128];
    int tid = threadIdx.x;
    int c = tid & 127;
    int half = tid >> 7;
    int q = c >> 5, c32 = c & 31;
    int v0 = blockIdx.x * 256;
    int vend = min(v0 + 256, n);
    float a1 = 0.f, a2 = 0.f;
    for (int v = v0 + half; v < vend; v += 2) {
        float x = bf2f(AGGB[((size_t)q * n + v) * 32 + c32]);
        a1 += x; a2 = fmaf(x, x, a2);
    }
    if (half == 0) { s1[c] = a1; s2[c] = a2; }
    __syncthreads();
    if (half == 1) { s1[c] += a1; s2[c] += a2; }
    __syncthreads();
    if (half == 0) {
        atomicAdd(&stats[c], s1[c]);
        atomicAdd(&stats[128 + c], s2[c]);
    }
}

extern "C" void kernel_launch(void* const* d_in, const int* in_sizes, int n_in,
                              void* d_out, int out_size, void* d_ws, size_t ws_size,
                              hipStream_t stream) {
    (void)n_in; (void)out_size; (void)ws_size;
    const float* x    = (const float*)d_in[0];
    const float* Win  = (const float*)d_in[1];
    const float* bin  = (const float*)d_in[2];
    const float* Wg   = (const float*)d_in[3];
    // d_in[4] = b_g: cancelled by BN mean-subtract, unused.
    const float* gamma = (const float*)d_in[5];
    const float* beta  = (const float*)d_in[6];
    const float* Wout  = (const float*)d_in[7];
    const float* bout  = (const float*)d_in[8];
    const int*   eidx  = (const int*)d_in[9];
    float* out = (float*)d_out;

    const int N = in_sizes[0] / 128;   // 50000 nodes
    const int E = in_sizes[9] / 2;     // 600000 edges
    const int* esrc_in = eidx;
    const int* edst_in = eidx + E;

    char* p = (char*)d_ws;
    auto alloc = [&](size_t bytes) { char* r = p; p += (bytes + 255) & ~(size_t)255; return r; };
    const size_t NB2 = (size_t)N * 128 * sizeof(unsigned short);
    unsigned short* h0b   = (unsigned short*)alloc(NB2);  // x_skip (bf16, row-major)
    unsigned short* tb16  = (unsigned short*)alloc(NB2);  // t (bf16, quarter-blocked)
    unsigned short* aggb  = (unsigned short*)alloc(NB2);  // agg (bf16, quarter-blocked)
    unsigned short* accb  = (unsigned short*)alloc(NB2);  // ACC (bf16, row-major)
    unsigned short* WinT  = (unsigned short*)alloc(128 * 128 * 2);
    unsigned short* WgT   = (unsigned short*)alloc(4 * 128 * 128 * 2);
    unsigned short* WoutT = (unsigned short*)alloc(128 * 64 * 2);
    float* disb  = (float*)alloc((size_t)N * 4);
    float* selfn = (float*)alloc((size_t)N * 4);
    // ---- contiguous zero region: cnt | bsum | boff | done | stats4 ----
    char* z0 = p;
    int*      cnt    = (int*)alloc((size_t)N * 4);
    unsigned* bsum   = (unsigned*)alloc(256 * 4);
    unsigned* boff   = (unsigned*)alloc(256 * 4);
    unsigned* done   = (unsigned*)alloc(256);
    float*    stats4 = (float*)alloc(4 * 256 * 4);
    const size_t zbytes = (size_t)(p - z0);
    int*   rowptr = (int*)alloc((size_t)(N + 1) * 4);
    int*   cursor = (int*)alloc((size_t)N * 4);
    unsigned long long* epack = (unsigned long long*)alloc((size_t)E * 8);

    auto cdiv = [](int a, int b) { return (a + b - 1) / b; };
    const int NBLK = cdiv(N, 256);     // 196 (must be <= 256 for scanall)
    const float inv_n = 1.0f / (float)N;
    // aggregate grid: 8 XIDs x K octet-rows; each wave handles ~8 nodes of its quarter
    const int K_AGG = cdiv(cdiv(N, 8), 8);
    const int QW    = 8 * K_AGG;       // waves per quarter

    // graph preprocessing (+ weight transposes fused into the hist launch)
    hipMemsetAsync(z0, 0, zbytes, stream);
    histw_kernel<<<cdiv(E, 256) + 352, 256, 0, stream>>>(edst_in, cnt, E,
                                                         Win, Wg, Wout, WinT, WgT, WoutT);
    scanall_kernel<<<NBLK, 256, 0, stream>>>(cnt, bsum, boff, done, rowptr, cursor,
                                             disb, selfn, N, NBLK);
    fill_kernel<<<cdiv(E, 256), 256, 0, stream>>>(esrc_in, edst_in, cursor, disb, epack, E);

    // fused startup: h0 = x@W_in+b_in ; t0 = h0@Wg[0]
    mgemm2_kernel<<<cdiv(N, 64), 256, 0, stream>>>(x, WinT, bin, WgT, h0b, tb16, N);

    for (int i = 0; i < 4; ++i) {
        float* stats = stats4 + i * 256;
        aggregate_kernel<<<8 * K_AGG, 256, 0, stream>>>(tb16, rowptr, epack, selfn,
                                                        aggb, N, QW);
        bn_stats_kernel<<<NBLK, 256, 0, stream>>>(aggb, stats, N);
        if (i < 3) {
            mgemm_bn_kernel<128, false, true><<<cdiv(N, 64), 256, 0, stream>>>(
                aggb, stats, gamma + i * 128, beta + i * 128, h0b, accb,
                WgT + (size_t)(i + 1) * 128 * 128, nullptr, (void*)tb16, N,
                inv_n, (i & 1), (i == 0) ? 1 : 0);
        } else {
            mgemm_bn_kernel<64, true, false><<<cdiv(N, 64), 256, 0, stream>>>(
                aggb, stats, gamma + i * 128, beta + i * 128, h0b, accb,
                WoutT, bout, (void*)out, N, inv_n, 1, 0);
        }
    }
}

// Round 4
// 421.770 us; speedup vs baseline: 1.8084x; 1.8084x over previous
//
#include <hip/hip_runtime.h>

using short8  = __attribute__((ext_vector_type(8))) short;
using floatx4 = __attribute__((ext_vector_type(4))) float;

// ---------- bf16 helpers ----------
static __device__ __forceinline__ float bf2f(unsigned short u) {
    union { unsigned u; float f; } v; v.u = ((unsigned)u) << 16; return v.f;
}
static __device__ __forceinline__ unsigned short f2bf(float f) {
    union { float f; unsigned u; } v; v.f = f;
    unsigned r = v.u + 0x7FFFu + ((v.u >> 16) & 1u);   // round-to-nearest-even
    return (unsigned short)(r >> 16);
}

// ---------- fused: degree histogram + all weight transposes (independent work) ----------
__global__ void histw_kernel(const int* __restrict__ dst, int* __restrict__ cnt, int E,
                             const float* __restrict__ Win, const float* __restrict__ Wg,
                             const float* __restrict__ Wout,
                             unsigned short* __restrict__ WinT, unsigned short* __restrict__ WgT,
                             unsigned short* __restrict__ WoutT) {
    int HB = (E + 255) >> 8;
    int b = blockIdx.x;
    if (b < HB) {
        int i = b * 256 + threadIdx.x;
        if (i < E) atomicAdd(&cnt[dst[i]], 1);
    } else {
        int i = (b - HB) * 256 + threadIdx.x;
        if (i < 16384) {                       // Win 128x128
            int m = i & 127, k = i >> 7;
            WinT[m * 128 + k] = f2bf(Win[i]);
        } else if (i < 81920) {                // Wg 4x128x128
            int j = i - 16384;
            int m = j & 127, k = (j >> 7) & 127, mat = j >> 14;
            WgT[mat * 16384 + m * 128 + k] = f2bf(Wg[j]);
        } else if (i < 90112) {                // Wout 128x64
            int j = i - 81920;
            int m = j % 64, k = j / 64;
            WoutT[m * 128 + k] = f2bf(Wout[j]);
        }
    }
}

// ---------- single-kernel exclusive scan over cnt[0..n), nb <= 256 blocks ----------
__global__ __launch_bounds__(256) void scanall_kernel(const int* __restrict__ cnt,
        unsigned* __restrict__ bsum, unsigned* __restrict__ boff, unsigned* __restrict__ done,
        int* __restrict__ rowptr, int* __restrict__ cursor,
        float* __restrict__ dis, float* __restrict__ selfn, int n, int nb) {
    __shared__ int s[256];
    __shared__ int s2[256];
    __shared__ int flag_agg;
    __shared__ int blkoff;
    const int b = blockIdx.x, tid = threadIdx.x;
    int i = b * 256 + tid;
    int cc = (i < n) ? cnt[i] : 0;
    s[tid] = cc;
    __syncthreads();
    for (int off = 1; off < 256; off <<= 1) {   // inclusive scan in LDS
        int t = s[tid];
        int a = (tid >= off) ? s[tid - off] : 0;
        __syncthreads();
        s[tid] = t + a;
        __syncthreads();
    }
    if (tid == 0) {
        atomicExch(&bsum[b], (unsigned)s[255] | 0x80000000u);   // publish block total
        __threadfence();                                        // release
        unsigned t = atomicAdd(done, 1u);
        flag_agg = (t == (unsigned)(nb - 1)) ? 1 : 0;           // last arrival aggregates
    }
    __syncthreads();
    if (flag_agg) {
        __threadfence();                                        // acquire
        unsigned val = (tid < nb) ? (atomicOr(&bsum[tid], 0u) & 0x7fffffffu) : 0u;
        s2[tid] = (int)val;
        __syncthreads();
        for (int off = 1; off < 256; off <<= 1) {
            int t = s2[tid];
            int a = (tid >= off) ? s2[tid - off] : 0;
            __syncthreads();
            s2[tid] = t + a;
            __syncthreads();
        }
        if (tid < nb)
            atomicExch(&boff[tid], ((unsigned)s2[tid] - val) | 0x80000000u); // exclusive
    }
    if (tid == 0) {
        unsigned vv;
        while (((vv = atomicOr(&boff[b], 0u)) & 0x80000000u) == 0u)
            __builtin_amdgcn_s_sleep(8);
        blkoff = (int)(vv & 0x7fffffffu);
    }
    __syncthreads();
    if (i < n) {
        int pre = blkoff + s[tid] - cc;       // exclusive prefix
        rowptr[i] = pre;
        cursor[i] = pre;
        float d = (float)cc + 1.0f;           // deg = in-degree + self-loop
        dis[i] = rsqrtf(d);
        selfn[i] = 1.0f / d;
        if (i == n - 1) rowptr[n] = pre + cc;
    }
}

// ---------- CSR fill: packed {src, w=dis[s]*dis[d]} per edge (8B scattered store) ----------
__global__ void fill_kernel(const int* __restrict__ src, const int* __restrict__ dst,
        int* __restrict__ cursor, const float* __restrict__ dis,
        unsigned long long* __restrict__ epack, int E) {
    int i = blockIdx.x * 256 + threadIdx.x;
    if (i < E) {
        int s = src[i], d = dst[i];
        int p = atomicAdd(&cursor[d], 1);
        float w = dis[s] * dis[d];            // edge weight, constant across all 4 layers
        unsigned long long rec = (unsigned long long)(unsigned)s |
                                 ((unsigned long long)__float_as_uint(w) << 32);
        epack[p] = rec;
    }
}

// ---------- fused startup: h0 = x@W1 + b1 (bf16 out), t0 = h0@W2 (bf16 out) ----------
__global__ __launch_bounds__(256) void mgemm2_kernel(
        const float* __restrict__ X,
        const unsigned short* __restrict__ W1T, const float* __restrict__ b1,
        const unsigned short* __restrict__ W2T,
        unsigned short* __restrict__ H0, unsigned short* __restrict__ T0, int nrows) {
    __shared__ unsigned short Al[64 * 136];
    __shared__ unsigned short Wl[128 * 136];
    const int tid   = threadIdx.x;
    const int w     = tid >> 6;
    const int lane  = tid & 63;
    const int col_l = lane & 15;
    const int quad  = lane >> 4;
    const int row_base = blockIdx.x * 64;

#pragma unroll
    for (int it = 0; it < 8; ++it) {
        int idx = it * 256 + tid;
        int r = idx >> 5, c4 = idx & 31;
        int gr = row_base + r; if (gr >= nrows) gr = nrows - 1;
        float4 v = *(const float4*)&X[(size_t)gr * 128 + c4 * 4];
        ushort4 u;
        u.x = f2bf(v.x); u.y = f2bf(v.y); u.z = f2bf(v.z); u.w = f2bf(v.w);
        *(ushort4*)&Al[r * 136 + c4 * 4] = u;
    }
#pragma unroll
    for (int it = 0; it < 8; ++it) {
        int idx = it * 256 + tid;
        int r = idx >> 4, ch = idx & 15;
        *(float4*)&Wl[r * 136 + ch * 8] = *(const float4*)&W1T[(size_t)r * 128 + ch * 8];
    }
    __syncthreads();

    short8 af[4];
    const int arow = w * 16 + col_l;
#pragma unroll
    for (int ks = 0; ks < 4; ++ks)
        af[ks] = *(const short8*)&Al[arow * 136 + ks * 32 + quad * 8];

    floatx4 acc[8];
#pragma unroll
    for (int ct = 0; ct < 8; ++ct) {
        acc[ct] = (floatx4){0.f, 0.f, 0.f, 0.f};
#pragma unroll
        for (int ks = 0; ks < 4; ++ks) {
            short8 bf = *(const short8*)&Wl[(ct * 16 + col_l) * 136 + ks * 32 + quad * 8];
            acc[ct] = __builtin_amdgcn_mfma_f32_16x16x32_bf16(af[ks], bf, acc[ct], 0, 0, 0);
        }
    }
    __syncthreads();   // all LDS reads done before overwrite

#pragma unroll
    for (int ct = 0; ct < 8; ++ct) {
        int col = ct * 16 + col_l;
        float bv = b1[col];
#pragma unroll
        for (int r = 0; r < 4; ++r) {
            int row_l = w * 16 + quad * 4 + r;
            float o = acc[ct][r] + bv;
            unsigned short ob = f2bf(o);
            Al[row_l * 136 + col] = ob;
            int gr = row_base + row_l;
            if (gr < nrows) H0[(size_t)gr * 128 + col] = ob;
        }
    }
#pragma unroll
    for (int it = 0; it < 8; ++it) {
        int idx = it * 256 + tid;
        int r = idx >> 4, ch = idx & 15;
        *(float4*)&Wl[r * 136 + ch * 8] = *(const float4*)&W2T[(size_t)r * 128 + ch * 8];
    }
    __syncthreads();

#pragma unroll
    for (int ks = 0; ks < 4; ++ks)
        af[ks] = *(const short8*)&Al[arow * 136 + ks * 32 + quad * 8];
#pragma unroll
    for (int ct = 0; ct < 8; ++ct) {
        acc[ct] = (floatx4){0.f, 0.f, 0.f, 0.f};
#pragma unroll
        for (int ks = 0; ks < 4; ++ks) {
            short8 bf = *(const short8*)&Wl[(ct * 16 + col_l) * 136 + ks * 32 + quad * 8];
            acc[ct] = __builtin_amdgcn_mfma_f32_16x16x32_bf16(af[ks], bf, acc[ct], 0, 0, 0);
        }
    }
#pragma unroll
    for (int ct = 0; ct < 8; ++ct) {
        int col = ct * 16 + col_l;
#pragma unroll
        for (int r = 0; r < 4; ++r) {
            int gr = row_base + w * 16 + quad * 4 + r;
            if (gr < nrows) T0[(size_t)gr * 128 + col] = f2bf(acc[ct][r]);
        }
    }
}

// ---------- fused BN(+skip+relu+ACC[bf16]) -> MFMA GEMM (AGG bf16) ----------
// stats come as 8 shards of 256 floats (sum[128], sumsq[128]); summed here.
template<int MO, bool STAGE_ACC, bool OB16>
__global__ __launch_bounds__(256) void mgemm_bn_kernel(
        const unsigned short* __restrict__ AGGB, const float* __restrict__ stats,
        const float* __restrict__ gamma, const float* __restrict__ beta,
        const unsigned short* __restrict__ XSKIP, unsigned short* __restrict__ ACC,
        const unsigned short* __restrict__ WT, const float* __restrict__ bias,
        void* __restrict__ C, int nrows, float inv_n, int do_skip, int first) {
    constexpr int NT = MO / 16;
    __shared__ unsigned short Al[64 * 136];
    __shared__ unsigned short Wl[MO * 136];
    __shared__ float ABl[256];
    const int tid   = threadIdx.x;
    const int w     = tid >> 6;
    const int lane  = tid & 63;
    const int col_l = lane & 15;
    const int quad  = lane >> 4;
    const int row_base = blockIdx.x * 64;

    if (tid < 128) {
        float s = 0.f, ss = 0.f;
#pragma unroll
        for (int k = 0; k < 8; ++k) {
            s  += stats[k * 256 + tid];
            ss += stats[k * 256 + 128 + tid];
        }
        float m = s * inv_n;
        float var = ss * inv_n - m * m;
        float inv = rsqrtf(var + 1e-5f);
        float Ax = inv * gamma[tid];
        ABl[tid] = Ax;
        ABl[128 + tid] = beta[tid] - m * Ax;
    }
#pragma unroll
    for (int it = 0; it < MO / 16; ++it) {
        int idx = it * 256 + tid;
        int r = idx >> 4, ch = idx & 15;
        *(float4*)&Wl[r * 136 + ch * 8] = *(const float4*)&WT[(size_t)r * 128 + ch * 8];
    }
    __syncthreads();

#pragma unroll
    for (int it = 0; it < 8; ++it) {
        int idx = it * 256 + tid;
        int r = idx >> 5, c4 = idx & 31;
        int gr = row_base + r;
        ushort4 hu = make_ushort4(0, 0, 0, 0);
        if (gr < nrows) {
            ushort4 xb = *(const ushort4*)&AGGB[(size_t)gr * 128 + c4 * 4];
            float4 Av = ((const float4*)ABl)[c4];
            float4 Bv = ((const float4*)ABl)[32 + c4];
            float4 t;
            t.x = fmaf(bf2f(xb.x), Av.x, Bv.x);
            t.y = fmaf(bf2f(xb.y), Av.y, Bv.y);
            t.z = fmaf(bf2f(xb.z), Av.z, Bv.z);
            t.w = fmaf(bf2f(xb.w), Av.w, Bv.w);
            if (do_skip) {
                ushort4 sk = *(const ushort4*)&XSKIP[(size_t)gr * 128 + c4 * 4];
                t.x = fmaf(0.5f, bf2f(sk.x), t.x);
                t.y = fmaf(0.5f, bf2f(sk.y), t.y);
                t.z = fmaf(0.5f, bf2f(sk.z), t.z);
                t.w = fmaf(0.5f, bf2f(sk.w), t.w);
            }
            t.x = fmaxf(t.x, 0.f); t.y = fmaxf(t.y, 0.f);
            t.z = fmaxf(t.z, 0.f); t.w = fmaxf(t.w, 0.f);
            float4 a;
            if (first) {
                a = t;
            } else {
                ushort4 ab = *(const ushort4*)&ACC[(size_t)gr * 128 + c4 * 4];
                a.x = bf2f(ab.x) + t.x;
                a.y = bf2f(ab.y) + t.y;
                a.z = bf2f(ab.z) + t.z;
                a.w = bf2f(ab.w) + t.w;
            }
            float4 sv;
            if (STAGE_ACC) sv = a; else sv = t;
            hu.x = f2bf(sv.x); hu.y = f2bf(sv.y); hu.z = f2bf(sv.z); hu.w = f2bf(sv.w);
            if (!STAGE_ACC) {
                ushort4 au;
                au.x = f2bf(a.x); au.y = f2bf(a.y); au.z = f2bf(a.z); au.w = f2bf(a.w);
                *(ushort4*)&ACC[(size_t)gr * 128 + c4 * 4] = au;
            }
        }
        *(ushort4*)&Al[r * 136 + c4 * 4] = hu;
    }
    __syncthreads();

    short8 af[4];
    const int arow = w * 16 + col_l;
#pragma unroll
    for (int ks = 0; ks < 4; ++ks)
        af[ks] = *(const short8*)&Al[arow * 136 + ks * 32 + quad * 8];

    floatx4 acc[NT];
#pragma unroll
    for (int ct = 0; ct < NT; ++ct) {
        acc[ct] = (floatx4){0.f, 0.f, 0.f, 0.f};
#pragma unroll
        for (int ks = 0; ks < 4; ++ks) {
            short8 bf = *(const short8*)&Wl[(ct * 16 + col_l) * 136 + ks * 32 + quad * 8];
            acc[ct] = __builtin_amdgcn_mfma_f32_16x16x32_bf16(af[ks], bf, acc[ct], 0, 0, 0);
        }
    }

#pragma unroll
    for (int ct = 0; ct < NT; ++ct) {
        int col = ct * 16 + col_l;
        float bv = bias ? bias[col] : 0.f;
#pragma unroll
        for (int r = 0; r < 4; ++r) {
            int gr = row_base + w * 16 + quad * 4 + r;
            if (gr < nrows) {
                float o = acc[ct][r] + bv;
                if (OB16) ((unsigned short*)C)[(size_t)gr * MO + col] = f2bf(o);
                else      ((float*)C)[(size_t)gr * MO + col] = o;
            }
        }
    }
}

// ---------- persistent CSR gather aggregation + fused BN stats ----------
// One wave per node per iteration (row-major T, 256B wave gathers, R1 form).
// Stats accumulated in registers over the wave's nodes, LDS-reduced across the
// block's 4 waves, then atomicAdd into shard blockIdx&7 (depth nblocks/8 per addr).
__global__ __launch_bounds__(256) void aggstat_kernel(const unsigned short* __restrict__ T,
        const int* __restrict__ rowptr, const unsigned long long* __restrict__ epack,
        const float* __restrict__ selfn,
        unsigned short* __restrict__ AGGB, float* __restrict__ stats, int n, int nw) {
    const int w    = threadIdx.x >> 6;
    const int lane = threadIdx.x & 63;
    const int wid  = blockIdx.x * 4 + w;
    const int c    = lane * 2;
    float s1x = 0.f, s1y = 0.f, s2x = 0.f, s2y = 0.f;

    for (int v = wid; v < n; v += nw) {
        ushort2 tv = *(const ushort2*)&T[(size_t)v * 128 + c];
        float sn = selfn[v];
        float ax = bf2f(tv.x) * sn, ay = bf2f(tv.y) * sn;
        int e = rowptr[v], e1 = rowptr[v + 1];
        for (; e + 8 <= e1; e += 8) {
            unsigned long long d[8]; ushort2 t[8];
#pragma unroll
            for (int j = 0; j < 8; ++j) d[j] = __builtin_nontemporal_load(&epack[e + j]);
#pragma unroll
            for (int j = 0; j < 8; ++j)
                t[j] = *(const ushort2*)&T[(size_t)(unsigned)d[j] * 128 + c];
#pragma unroll
            for (int j = 0; j < 8; ++j) {
                float wj = __uint_as_float((unsigned)(d[j] >> 32));
                ax = fmaf(wj, bf2f(t[j].x), ax);
                ay = fmaf(wj, bf2f(t[j].y), ay);
            }
        }
        for (; e + 4 <= e1; e += 4) {
            unsigned long long d[4]; ushort2 t[4];
#pragma unroll
            for (int j = 0; j < 4; ++j) d[j] = __builtin_nontemporal_load(&epack[e + j]);
#pragma unroll
            for (int j = 0; j < 4; ++j)
                t[j] = *(const ushort2*)&T[(size_t)(unsigned)d[j] * 128 + c];
#pragma unroll
            for (int j = 0; j < 4; ++j) {
                float wj = __uint_as_float((unsigned)(d[j] >> 32));
                ax = fmaf(wj, bf2f(t[j].x), ax);
                ay = fmaf(wj, bf2f(t[j].y), ay);
            }
        }
        for (; e < e1; ++e) {
            unsigned long long d0 = __builtin_nontemporal_load(&epack[e]);
            ushort2 tu = *(const ushort2*)&T[(size_t)(unsigned)d0 * 128 + c];
            float w0 = __uint_as_float((unsigned)(d0 >> 32));
            ax = fmaf(w0, bf2f(tu.x), ax);
            ay = fmaf(w0, bf2f(tu.y), ay);
        }
        ushort2 o; o.x = f2bf(ax); o.y = f2bf(ay);
        *(ushort2*)&AGGB[(size_t)v * 128 + c] = o;
        float rx = bf2f(o.x), ry = bf2f(o.y);   // stats on bf16-rounded values (matches old bn_stats)
        s1x += rx; s1y += ry;
        s2x = fmaf(rx, rx, s2x); s2y = fmaf(ry, ry, s2y);
    }

    __shared__ float r1[4][130];
    __shared__ float r2[4][130];
    r1[w][c] = s1x; r1[w][c + 1] = s1y;
    r2[w][c] = s2x; r2[w][c + 1] = s2y;
    __syncthreads();
    if (w == 0) {
        float a1 = r1[0][c] + r1[1][c] + r1[2][c] + r1[3][c];
        float b1 = r1[0][c + 1] + r1[1][c + 1] + r1[2][c + 1] + r1[3][c + 1];
        float a2 = r2[0][c] + r2[1][c] + r2[2][c] + r2[3][c];
        float b2 = r2[0][c + 1] + r2[1][c + 1] + r2[2][c + 1] + r2[3][c + 1];
        float* sh = stats + (blockIdx.x & 7) * 256;
        atomicAdd(&sh[c], a1);
        atomicAdd(&sh[c + 1], b1);
        atomicAdd(&sh[128 + c], a2);
        atomicAdd(&sh[128 + c + 1], b2);
    }
}

extern "C" void kernel_launch(void* const* d_in, const int* in_sizes, int n_in,
                              void* d_out, int out_size, void* d_ws, size_t ws_size,
                              hipStream_t stream) {
    (void)n_in; (void)out_size; (void)ws_size;
    const float* x    = (const float*)d_in[0];
    const float* Win  = (const float*)d_in[1];
    const float* bin  = (const float*)d_in[2];
    const float* Wg   = (const float*)d_in[3];
    // d_in[4] = b_g: cancelled by BN mean-subtract, unused.
    const float* gamma = (const float*)d_in[5];
    const float* beta  = (const float*)d_in[6];
    const float* Wout  = (const float*)d_in[7];
    const float* bout  = (const float*)d_in[8];
    const int*   eidx  = (const int*)d_in[9];
    float* out = (float*)d_out;

    const int N = in_sizes[0] / 128;   // 50000 nodes
    const int E = in_sizes[9] / 2;     // 600000 edges
    const int* esrc_in = eidx;
    const int* edst_in = eidx + E;

    char* p = (char*)d_ws;
    auto alloc = [&](size_t bytes) { char* r = p; p += (bytes + 255) & ~(size_t)255; return r; };
    const size_t NB2 = (size_t)N * 128 * sizeof(unsigned short);
    unsigned short* h0b   = (unsigned short*)alloc(NB2);  // x_skip (bf16)
    unsigned short* tb16  = (unsigned short*)alloc(NB2);  // t (bf16)
    unsigned short* aggb  = (unsigned short*)alloc(NB2);  // agg (bf16)
    unsigned short* accb  = (unsigned short*)alloc(NB2);  // ACC (bf16)
    unsigned short* WinT  = (unsigned short*)alloc(128 * 128 * 2);
    unsigned short* WgT   = (unsigned short*)alloc(4 * 128 * 128 * 2);
    unsigned short* WoutT = (unsigned short*)alloc(128 * 64 * 2);
    float* disb  = (float*)alloc((size_t)N * 4);
    float* selfn = (float*)alloc((size_t)N * 4);
    // ---- contiguous zero region: cnt | bsum | boff | done | stats4 ----
    char* z0 = p;
    int*      cnt    = (int*)alloc((size_t)N * 4);
    unsigned* bsum   = (unsigned*)alloc(256 * 4);
    unsigned* boff   = (unsigned*)alloc(256 * 4);
    unsigned* done   = (unsigned*)alloc(256);
    float*    stats4 = (float*)alloc((size_t)4 * 8 * 256 * 4);   // [layer][shard 0..7][256]
    const size_t zbytes = (size_t)(p - z0);
    int*   rowptr = (int*)alloc((size_t)(N + 1) * 4);
    int*   cursor = (int*)alloc((size_t)N * 4);
    unsigned long long* epack = (unsigned long long*)alloc((size_t)E * 8);

    auto cdiv = [](int a, int b) { return (a + b - 1) / b; };
    const int NBLK = cdiv(N, 256);     // 196 (must be <= 256 for scanall)
    const float inv_n = 1.0f / (float)N;
    const int AGG_BLOCKS = 2048;       // 8192 waves = full residency; ~6 nodes/wave
    const int AGG_WAVES  = AGG_BLOCKS * 4;

    // graph preprocessing (+ weight transposes fused into the hist launch)
    hipMemsetAsync(z0, 0, zbytes, stream);
    histw_kernel<<<cdiv(E, 256) + 352, 256, 0, stream>>>(edst_in, cnt, E,
                                                         Win, Wg, Wout, WinT, WgT, WoutT);
    scanall_kernel<<<NBLK, 256, 0, stream>>>(cnt, bsum, boff, done, rowptr, cursor,
                                             disb, selfn, N, NBLK);
    fill_kernel<<<cdiv(E, 256), 256, 0, stream>>>(esrc_in, edst_in, cursor, disb, epack, E);

    // fused startup: h0 = x@W_in+b_in ; t0 = h0@Wg[0]
    mgemm2_kernel<<<cdiv(N, 64), 256, 0, stream>>>(x, WinT, bin, WgT, h0b, tb16, N);

    for (int i = 0; i < 4; ++i) {
        float* stats = stats4 + (size_t)i * 8 * 256;
        aggstat_kernel<<<AGG_BLOCKS, 256, 0, stream>>>(tb16, rowptr, epack, selfn,
                                                       aggb, stats, N, AGG_WAVES);
        if (i < 3) {
            mgemm_bn_kernel<128, false, true><<<cdiv(N, 64), 256, 0, stream>>>(
                aggb, stats, gamma + i * 128, beta + i * 128, h0b, accb,
                WgT + (size_t)(i + 1) * 128 * 128, nullptr, (void*)tb16, N,
                inv_n, (i & 1), (i == 0) ? 1 : 0);
        } else {
            mgemm_bn_kernel<64, true, false><<<cdiv(N, 64), 256, 0, stream>>>(
                aggb, stats, gamma + i * 128, beta + i * 128, h0b, accb,
                WoutT, bout, (void*)out, N, inv_n, 1, 0);
        }
    }
}

// Round 5
// 417.437 us; speedup vs baseline: 1.8271x; 1.0104x over previous
//
#include <hip/hip_runtime.h>

using short8  = __attribute__((ext_vector_type(8))) short;
using floatx4 = __attribute__((ext_vector_type(4))) float;

// ---------- bf16 helpers ----------
static __device__ __forceinline__ float bf2f(unsigned short u) {
    union { unsigned u; float f; } v; v.u = ((unsigned)u) << 16; return v.f;
}
static __device__ __forceinline__ unsigned short f2bf(float f) {
    union { float f; unsigned u; } v; v.f = f;
    unsigned r = v.u + 0x7FFFu + ((v.u >> 16) & 1u);   // round-to-nearest-even
    return (unsigned short)(r >> 16);
}

// ---------- fused: degree histogram + all weight transposes (independent work) ----------
__global__ void histw_kernel(const int* __restrict__ dst, int* __restrict__ cnt, int E,
                             const float* __restrict__ Win, const float* __restrict__ Wg,
                             const float* __restrict__ Wout,
                             unsigned short* __restrict__ WinT, unsigned short* __restrict__ WgT,
                             unsigned short* __restrict__ WoutT) {
    int HB = (E + 255) >> 8;
    int b = blockIdx.x;
    if (b < HB) {
        int i = b * 256 + threadIdx.x;
        if (i < E) atomicAdd(&cnt[dst[i]], 1);
    } else {
        int i = (b - HB) * 256 + threadIdx.x;
        if (i < 16384) {                       // Win 128x128
            int m = i & 127, k = i >> 7;
            WinT[m * 128 + k] = f2bf(Win[i]);
        } else if (i < 81920) {                // Wg 4x128x128
            int j = i - 16384;
            int m = j & 127, k = (j >> 7) & 127, mat = j >> 14;
            WgT[mat * 16384 + m * 128 + k] = f2bf(Wg[j]);
        } else if (i < 90112) {                // Wout 128x64
            int j = i - 81920;
            int m = j % 64, k = j / 64;
            WoutT[m * 128 + k] = f2bf(Wout[j]);
        }
    }
}

// ---------- single-kernel exclusive scan over cnt[0..n), nb <= 256 blocks ----------
__global__ __launch_bounds__(256) void scanall_kernel(const int* __restrict__ cnt,
        unsigned* __restrict__ bsum, unsigned* __restrict__ boff, unsigned* __restrict__ done,
        int* __restrict__ rowptr, int* __restrict__ cursor,
        float* __restrict__ dis, float* __restrict__ selfn, int n, int nb) {
    __shared__ int s[256];
    __shared__ int s2[256];
    __shared__ int flag_agg;
    __shared__ int blkoff;
    const int b = blockIdx.x, tid = threadIdx.x;
    int i = b * 256 + tid;
    int cc = (i < n) ? cnt[i] : 0;
    s[tid] = cc;
    __syncthreads();
    for (int off = 1; off < 256; off <<= 1) {   // inclusive scan in LDS
        int t = s[tid];
        int a = (tid >= off) ? s[tid - off] : 0;
        __syncthreads();
        s[tid] = t + a;
        __syncthreads();
    }
    if (tid == 0) {
        atomicExch(&bsum[b], (unsigned)s[255] | 0x80000000u);   // publish block total
        __threadfence();                                        // release
        unsigned t = atomicAdd(done, 1u);
        flag_agg = (t == (unsigned)(nb - 1)) ? 1 : 0;           // last arrival aggregates
    }
    __syncthreads();
    if (flag_agg) {
        __threadfence();                                        // acquire
        unsigned val = (tid < nb) ? (atomicOr(&bsum[tid], 0u) & 0x7fffffffu) : 0u;
        s2[tid] = (int)val;
        __syncthreads();
        for (int off = 1; off < 256; off <<= 1) {
            int t = s2[tid];
            int a = (tid >= off) ? s2[tid - off] : 0;
            __syncthreads();
            s2[tid] = t + a;
            __syncthreads();
        }
        if (tid < nb)
            atomicExch(&boff[tid], ((unsigned)s2[tid] - val) | 0x80000000u); // exclusive
    }
    if (tid == 0) {
        unsigned vv;
        while (((vv = atomicOr(&boff[b], 0u)) & 0x80000000u) == 0u)
            __builtin_amdgcn_s_sleep(8);
        blkoff = (int)(vv & 0x7fffffffu);
    }
    __syncthreads();
    if (i < n) {
        int pre = blkoff + s[tid] - cc;       // exclusive prefix
        rowptr[i] = pre;
        cursor[i] = pre;
        float d = (float)cc + 1.0f;           // deg = in-degree + self-loop
        dis[i] = rsqrtf(d);
        selfn[i] = 1.0f / d;
        if (i == n - 1) rowptr[n] = pre + cc;
    }
}

// ---------- merged: mgemm2 (blocks [0,GB)) + CSR fill (blocks [GB, GB+FB)) ----------
// Independent work co-scheduled in one launch: MFMA-bound startup GEMMs overlap the
// write-allocate-bound edge scatter. Fill uses nontemporal 8B stores.
__global__ __launch_bounds__(256) void fillgemm_kernel(
        const float* __restrict__ X,
        const unsigned short* __restrict__ W1T, const float* __restrict__ b1,
        const unsigned short* __restrict__ W2T,
        unsigned short* __restrict__ H0, unsigned short* __restrict__ T0, int nrows, int GB,
        const int* __restrict__ src, const int* __restrict__ dst,
        int* __restrict__ cursor, const float* __restrict__ dis,
        unsigned long long* __restrict__ epack, int E) {
    __shared__ unsigned short Al[64 * 136];
    __shared__ unsigned short Wl[128 * 136];
    const int tid = threadIdx.x;

    if (blockIdx.x >= GB) {
        // ---------------- fill branch ----------------
        int i = (blockIdx.x - GB) * 256 + tid;
        if (i < E) {
            int s = src[i], d = dst[i];
            int p = atomicAdd(&cursor[d], 1);
            float w = dis[s] * dis[d];        // edge weight, constant across all 4 layers
            unsigned long long rec = (unsigned long long)(unsigned)s |
                                     ((unsigned long long)__float_as_uint(w) << 32);
            __builtin_nontemporal_store(rec, &epack[p]);
        }
        return;
    }

    // ---------------- mgemm2 branch ----------------
    const int w     = tid >> 6;
    const int lane  = tid & 63;
    const int col_l = lane & 15;
    const int quad  = lane >> 4;
    const int row_base = blockIdx.x * 64;

#pragma unroll
    for (int it = 0; it < 8; ++it) {
        int idx = it * 256 + tid;
        int r = idx >> 5, c4 = idx & 31;
        int gr = row_base + r; if (gr >= nrows) gr = nrows - 1;
        float4 v = *(const float4*)&X[(size_t)gr * 128 + c4 * 4];
        ushort4 u;
        u.x = f2bf(v.x); u.y = f2bf(v.y); u.z = f2bf(v.z); u.w = f2bf(v.w);
        *(ushort4*)&Al[r * 136 + c4 * 4] = u;
    }
#pragma unroll
    for (int it = 0; it < 8; ++it) {
        int idx = it * 256 + tid;
        int r = idx >> 4, ch = idx & 15;
        *(float4*)&Wl[r * 136 + ch * 8] = *(const float4*)&W1T[(size_t)r * 128 + ch * 8];
    }
    __syncthreads();

    short8 af[4];
    const int arow = w * 16 + col_l;
#pragma unroll
    for (int ks = 0; ks < 4; ++ks)
        af[ks] = *(const short8*)&Al[arow * 136 + ks * 32 + quad * 8];

    floatx4 acc[8];
#pragma unroll
    for (int ct = 0; ct < 8; ++ct) {
        acc[ct] = (floatx4){0.f, 0.f, 0.f, 0.f};
#pragma unroll
        for (int ks = 0; ks < 4; ++ks) {
            short8 bf = *(const short8*)&Wl[(ct * 16 + col_l) * 136 + ks * 32 + quad * 8];
            acc[ct] = __builtin_amdgcn_mfma_f32_16x16x32_bf16(af[ks], bf, acc[ct], 0, 0, 0);
        }
    }
    __syncthreads();   // all LDS reads done before overwrite

#pragma unroll
    for (int ct = 0; ct < 8; ++ct) {
        int col = ct * 16 + col_l;
        float bv = b1[col];
#pragma unroll
        for (int r = 0; r < 4; ++r) {
            int row_l = w * 16 + quad * 4 + r;
            float o = acc[ct][r] + bv;
            unsigned short ob = f2bf(o);
            Al[row_l * 136 + col] = ob;
            int gr = row_base + row_l;
            if (gr < nrows) H0[(size_t)gr * 128 + col] = ob;
        }
    }
#pragma unroll
    for (int it = 0; it < 8; ++it) {
        int idx = it * 256 + tid;
        int r = idx >> 4, ch = idx & 15;
        *(float4*)&Wl[r * 136 + ch * 8] = *(const float4*)&W2T[(size_t)r * 128 + ch * 8];
    }
    __syncthreads();

#pragma unroll
    for (int ks = 0; ks < 4; ++ks)
        af[ks] = *(const short8*)&Al[arow * 136 + ks * 32 + quad * 8];
#pragma unroll
    for (int ct = 0; ct < 8; ++ct) {
        acc[ct] = (floatx4){0.f, 0.f, 0.f, 0.f};
#pragma unroll
        for (int ks = 0; ks < 4; ++ks) {
            short8 bf = *(const short8*)&Wl[(ct * 16 + col_l) * 136 + ks * 32 + quad * 8];
            acc[ct] = __builtin_amdgcn_mfma_f32_16x16x32_bf16(af[ks], bf, acc[ct], 0, 0, 0);
        }
    }
#pragma unroll
    for (int ct = 0; ct < 8; ++ct) {
        int col = ct * 16 + col_l;
#pragma unroll
        for (int r = 0; r < 4; ++r) {
            int gr = row_base + w * 16 + quad * 4 + r;
            if (gr < nrows) T0[(size_t)gr * 128 + col] = f2bf(acc[ct][r]);
        }
    }
}

// ---------- fused BN(+skip+relu+ACC[bf16]) -> MFMA GEMM (AGG bf16) ----------
// stats come as 8 shards of 256 floats (sum[128], sumsq[128]); summed here.
template<int MO, bool STAGE_ACC, bool OB16>
__global__ __launch_bounds__(256) void mgemm_bn_kernel(
        const unsigned short* __restrict__ AGGB, const float* __restrict__ stats,
        const float* __restrict__ gamma, const float* __restrict__ beta,
        const unsigned short* __restrict__ XSKIP, unsigned short* __restrict__ ACC,
        const unsigned short* __restrict__ WT, const float* __restrict__ bias,
        void* __restrict__ C, int nrows, float inv_n, int do_skip, int first) {
    constexpr int NT = MO / 16;
    __shared__ unsigned short Al[64 * 136];
    __shared__ unsigned short Wl[MO * 136];
    __shared__ float ABl[256];
    const int tid   = threadIdx.x;
    const int w     = tid >> 6;
    const int lane  = tid & 63;
    const int col_l = lane & 15;
    const int quad  = lane >> 4;
    const int row_base = blockIdx.x * 64;

    if (tid < 128) {
        float s = 0.f, ss = 0.f;
#pragma unroll
        for (int k = 0; k < 8; ++k) {
            s  += stats[k * 256 + tid];
            ss += stats[k * 256 + 128 + tid];
        }
        float m = s * inv_n;
        float var = ss * inv_n - m * m;
        float inv = rsqrtf(var + 1e-5f);
        float Ax = inv * gamma[tid];
        ABl[tid] = Ax;
        ABl[128 + tid] = beta[tid] - m * Ax;
    }
#pragma unroll
    for (int it = 0; it < MO / 16; ++it) {
        int idx = it * 256 + tid;
        int r = idx >> 4, ch = idx & 15;
        *(float4*)&Wl[r * 136 + ch * 8] = *(const float4*)&WT[(size_t)r * 128 + ch * 8];
    }
    __syncthreads();

#pragma unroll
    for (int it = 0; it < 8; ++it) {
        int idx = it * 256 + tid;
        int r = idx >> 5, c4 = idx & 31;
        int gr = row_base + r;
        ushort4 hu = make_ushort4(0, 0, 0, 0);
        if (gr < nrows) {
            ushort4 xb = *(const ushort4*)&AGGB[(size_t)gr * 128 + c4 * 4];
            float4 Av = ((const float4*)ABl)[c4];
            float4 Bv = ((const float4*)ABl)[32 + c4];
            float4 t;
            t.x = fmaf(bf2f(xb.x), Av.x, Bv.x);
            t.y = fmaf(bf2f(xb.y), Av.y, Bv.y);
            t.z = fmaf(bf2f(xb.z), Av.z, Bv.z);
            t.w = fmaf(bf2f(xb.w), Av.w, Bv.w);
            if (do_skip) {
                ushort4 sk = *(const ushort4*)&XSKIP[(size_t)gr * 128 + c4 * 4];
                t.x = fmaf(0.5f, bf2f(sk.x), t.x);
                t.y = fmaf(0.5f, bf2f(sk.y), t.y);
                t.z = fmaf(0.5f, bf2f(sk.z), t.z);
                t.w = fmaf(0.5f, bf2f(sk.w), t.w);
            }
            t.x = fmaxf(t.x, 0.f); t.y = fmaxf(t.y, 0.f);
            t.z = fmaxf(t.z, 0.f); t.w = fmaxf(t.w, 0.f);
            float4 a;
            if (first) {
                a = t;
            } else {
                ushort4 ab = *(const ushort4*)&ACC[(size_t)gr * 128 + c4 * 4];
                a.x = bf2f(ab.x) + t.x;
                a.y = bf2f(ab.y) + t.y;
                a.z = bf2f(ab.z) + t.z;
                a.w = bf2f(ab.w) + t.w;
            }
            float4 sv;
            if (STAGE_ACC) sv = a; else sv = t;
            hu.x = f2bf(sv.x); hu.y = f2bf(sv.y); hu.z = f2bf(sv.z); hu.w = f2bf(sv.w);
            if (!STAGE_ACC) {
                ushort4 au;
                au.x = f2bf(a.x); au.y = f2bf(a.y); au.z = f2bf(a.z); au.w = f2bf(a.w);
                *(ushort4*)&ACC[(size_t)gr * 128 + c4 * 4] = au;
            }
        }
        *(ushort4*)&Al[r * 136 + c4 * 4] = hu;
    }
    __syncthreads();

    short8 af[4];
    const int arow = w * 16 + col_l;
#pragma unroll
    for (int ks = 0; ks < 4; ++ks)
        af[ks] = *(const short8*)&Al[arow * 136 + ks * 32 + quad * 8];

    floatx4 acc[NT];
#pragma unroll
    for (int ct = 0; ct < NT; ++ct) {
        acc[ct] = (floatx4){0.f, 0.f, 0.f, 0.f};
#pragma unroll
        for (int ks = 0; ks < 4; ++ks) {
            short8 bf = *(const short8*)&Wl[(ct * 16 + col_l) * 136 + ks * 32 + quad * 8];
            acc[ct] = __builtin_amdgcn_mfma_f32_16x16x32_bf16(af[ks], bf, acc[ct], 0, 0, 0);
        }
    }

#pragma unroll
    for (int ct = 0; ct < NT; ++ct) {
        int col = ct * 16 + col_l;
        float bv = bias ? bias[col] : 0.f;
#pragma unroll
        for (int r = 0; r < 4; ++r) {
            int gr = row_base + w * 16 + quad * 4 + r;
            if (gr < nrows) {
                float o = acc[ct][r] + bv;
                if (OB16) ((unsigned short*)C)[(size_t)gr * MO + col] = f2bf(o);
                else      ((float*)C)[(size_t)gr * MO + col] = o;
            }
        }
    }
}

// ---------- persistent CSR gather aggregation + fused BN stats ----------
__global__ __launch_bounds__(256) void aggstat_kernel(const unsigned short* __restrict__ T,
        const int* __restrict__ rowptr, const unsigned long long* __restrict__ epack,
        const float* __restrict__ selfn,
        unsigned short* __restrict__ AGGB, float* __restrict__ stats, int n, int nw) {
    const int w    = threadIdx.x >> 6;
    const int lane = threadIdx.x & 63;
    const int wid  = blockIdx.x * 4 + w;
    const int c    = lane * 2;
    float s1x = 0.f, s1y = 0.f, s2x = 0.f, s2y = 0.f;

    for (int v = wid; v < n; v += nw) {
        ushort2 tv = *(const ushort2*)&T[(size_t)v * 128 + c];
        float sn = selfn[v];
        float ax = bf2f(tv.x) * sn, ay = bf2f(tv.y) * sn;
        int e = rowptr[v], e1 = rowptr[v + 1];
        for (; e + 8 <= e1; e += 8) {
            unsigned long long d[8]; ushort2 t[8];
#pragma unroll
            for (int j = 0; j < 8; ++j) d[j] = __builtin_nontemporal_load(&epack[e + j]);
#pragma unroll
            for (int j = 0; j < 8; ++j)
                t[j] = *(const ushort2*)&T[(size_t)(unsigned)d[j] * 128 + c];
#pragma unroll
            for (int j = 0; j < 8; ++j) {
                float wj = __uint_as_float((unsigned)(d[j] >> 32));
                ax = fmaf(wj, bf2f(t[j].x), ax);
                ay = fmaf(wj, bf2f(t[j].y), ay);
            }
        }
        for (; e + 4 <= e1; e += 4) {
            unsigned long long d[4]; ushort2 t[4];
#pragma unroll
            for (int j = 0; j < 4; ++j) d[j] = __builtin_nontemporal_load(&epack[e + j]);
#pragma unroll
            for (int j = 0; j < 4; ++j)
                t[j] = *(const ushort2*)&T[(size_t)(unsigned)d[j] * 128 + c];
#pragma unroll
            for (int j = 0; j < 4; ++j) {
                float wj = __uint_as_float((unsigned)(d[j] >> 32));
                ax = fmaf(wj, bf2f(t[j].x), ax);
                ay = fmaf(wj, bf2f(t[j].y), ay);
            }
        }
        for (; e < e1; ++e) {
            unsigned long long d0 = __builtin_nontemporal_load(&epack[e]);
            ushort2 tu = *(const ushort2*)&T[(size_t)(unsigned)d0 * 128 + c];
            float w0 = __uint_as_float((unsigned)(d0 >> 32));
            ax = fmaf(w0, bf2f(tu.x), ax);
            ay = fmaf(w0, bf2f(tu.y), ay);
        }
        ushort2 o; o.x = f2bf(ax); o.y = f2bf(ay);
        *(ushort2*)&AGGB[(size_t)v * 128 + c] = o;
        float rx = bf2f(o.x), ry = bf2f(o.y);   // stats on bf16-rounded values
        s1x += rx; s1y += ry;
        s2x = fmaf(rx, rx, s2x); s2y = fmaf(ry, ry, s2y);
    }

    __shared__ float r1[4][130];
    __shared__ float r2[4][130];
    r1[w][c] = s1x; r1[w][c + 1] = s1y;
    r2[w][c] = s2x; r2[w][c + 1] = s2y;
    __syncthreads();
    if (w == 0) {
        float a1 = r1[0][c] + r1[1][c] + r1[2][c] + r1[3][c];
        float b1 = r1[0][c + 1] + r1[1][c + 1] + r1[2][c + 1] + r1[3][c + 1];
        float a2 = r2[0][c] + r2[1][c] + r2[2][c] + r2[3][c];
        float b2 = r2[0][c + 1] + r2[1][c + 1] + r2[2][c + 1] + r2[3][c + 1];
        float* sh = stats + (blockIdx.x & 7) * 256;
        atomicAdd(&sh[c], a1);
        atomicAdd(&sh[c + 1], b1);
        atomicAdd(&sh[128 + c], a2);
        atomicAdd(&sh[128 + c + 1], b2);
    }
}

extern "C" void kernel_launch(void* const* d_in, const int* in_sizes, int n_in,
                              void* d_out, int out_size, void* d_ws, size_t ws_size,
                              hipStream_t stream) {
    (void)n_in; (void)out_size; (void)ws_size;
    const float* x    = (const float*)d_in[0];
    const float* Win  = (const float*)d_in[1];
    const float* bin  = (const float*)d_in[2];
    const float* Wg   = (const float*)d_in[3];
    // d_in[4] = b_g: cancelled by BN mean-subtract, unused.
    const float* gamma = (const float*)d_in[5];
    const float* beta  = (const float*)d_in[6];
    const float* Wout  = (const float*)d_in[7];
    const float* bout  = (const float*)d_in[8];
    const int*   eidx  = (const int*)d_in[9];
    float* out = (float*)d_out;

    const int N = in_sizes[0] / 128;   // 50000 nodes
    const int E = in_sizes[9] / 2;     // 600000 edges
    const int* esrc_in = eidx;
    const int* edst_in = eidx + E;

    char* p = (char*)d_ws;
    auto alloc = [&](size_t bytes) { char* r = p; p += (bytes + 255) & ~(size_t)255; return r; };
    const size_t NB2 = (size_t)N * 128 * sizeof(unsigned short);
    unsigned short* h0b   = (unsigned short*)alloc(NB2);  // x_skip (bf16)
    unsigned short* tb16  = (unsigned short*)alloc(NB2);  // t (bf16)
    unsigned short* aggb  = (unsigned short*)alloc(NB2);  // agg (bf16)
    unsigned short* accb  = (unsigned short*)alloc(NB2);  // ACC (bf16)
    unsigned short* WinT  = (unsigned short*)alloc(128 * 128 * 2);
    unsigned short* WgT   = (unsigned short*)alloc(4 * 128 * 128 * 2);
    unsigned short* WoutT = (unsigned short*)alloc(128 * 64 * 2);
    float* disb  = (float*)alloc((size_t)N * 4);
    float* selfn = (float*)alloc((size_t)N * 4);
    // ---- contiguous zero region: cnt | bsum | boff | done | stats4 ----
    char* z0 = p;
    int*      cnt    = (int*)alloc((size_t)N * 4);
    unsigned* bsum   = (unsigned*)alloc(256 * 4);
    unsigned* boff   = (unsigned*)alloc(256 * 4);
    unsigned* done   = (unsigned*)alloc(256);
    float*    stats4 = (float*)alloc((size_t)4 * 8 * 256 * 4);   // [layer][shard 0..7][256]
    const size_t zbytes = (size_t)(p - z0);
    int*   rowptr = (int*)alloc((size_t)(N + 1) * 4);
    int*   cursor = (int*)alloc((size_t)N * 4);
    unsigned long long* epack = (unsigned long long*)alloc((size_t)E * 8);

    auto cdiv = [](int a, int b) { return (a + b - 1) / b; };
    const int NBLK = cdiv(N, 256);     // 196 (must be <= 256 for scanall)
    const float inv_n = 1.0f / (float)N;
    const int AGG_BLOCKS = 2048;       // 8192 waves = full residency; ~6 nodes/wave
    const int AGG_WAVES  = AGG_BLOCKS * 4;
    const int GB = cdiv(N, 64);        // mgemm2 tile blocks (782)
    const int FB = cdiv(E, 256);       // fill blocks (2344)

    // graph preprocessing (+ weight transposes fused into the hist launch)
    hipMemsetAsync(z0, 0, zbytes, stream);
    histw_kernel<<<cdiv(E, 256) + 352, 256, 0, stream>>>(edst_in, cnt, E,
                                                         Win, Wg, Wout, WinT, WgT, WoutT);
    scanall_kernel<<<NBLK, 256, 0, stream>>>(cnt, bsum, boff, done, rowptr, cursor,
                                             disb, selfn, N, NBLK);

    // merged: startup GEMMs (h0 = x@W_in+b_in ; t0 = h0@Wg[0]) || CSR fill
    fillgemm_kernel<<<GB + FB, 256, 0, stream>>>(x, WinT, bin, WgT, h0b, tb16, N, GB,
                                                 esrc_in, edst_in, cursor, disb, epack, E);

    for (int i = 0; i < 4; ++i) {
        float* stats = stats4 + (size_t)i * 8 * 256;
        aggstat_kernel<<<AGG_BLOCKS, 256, 0, stream>>>(tb16, rowptr, epack, selfn,
                                                       aggb, stats, N, AGG_WAVES);
        if (i < 3) {
            mgemm_bn_kernel<128, false, true><<<cdiv(N, 64), 256, 0, stream>>>(
                aggb, stats, gamma + i * 128, beta + i * 128, h0b, accb,
                WgT + (size_t)(i + 1) * 128 * 128, nullptr, (void*)tb16, N,
                inv_n, (i & 1), (i == 0) ? 1 : 0);
        } else {
            mgemm_bn_kernel<64, true, false><<<cdiv(N, 64), 256, 0, stream>>>(
                aggb, stats, gamma + i * 128, beta + i * 128, h0b, accb,
                WoutT, bout, (void*)out, N, inv_n, 1, 0);
        }
    }
}